// Round 3
// baseline (135.316 us; speedup 1.0000x reference)
//
#include <hip/hip_runtime.h>
#include <hip/hip_bf16.h>

typedef __attribute__((ext_vector_type(8))) short short8;
typedef __attribute__((ext_vector_type(8))) __bf16 bf16x8;
typedef __attribute__((ext_vector_type(4))) float f32x4;

#define MFMA(a, b, c) __builtin_amdgcn_mfma_f32_16x16x32_bf16((a), (b), (c), 0, 0, 0)
#define SCALE 0.0625f

static __device__ __forceinline__ void gload16(const void* g, void* l) {
  __builtin_amdgcn_global_load_lds(
      (const __attribute__((address_space(1))) void*)g,
      (__attribute__((address_space(3))) void*)l, 16, 0, 0);
}

static __device__ __forceinline__ unsigned short f2b(float f) {
  union { __hip_bfloat16 h; unsigned short u; } cv;
  cv.h = __float2bfloat16(f);
  return cv.u;
}

// ---- x (f32) -> bf16, 8 elems/thread ---------------------------------------
__global__ __launch_bounds__(256) void convert_x_kern(const float* __restrict__ x,
                                                      unsigned short* __restrict__ xb) {
  long i = ((long)blockIdx.x * 256 + threadIdx.x) * 8;
  float4 a = *reinterpret_cast<const float4*>(x + i);
  float4 b = *reinterpret_cast<const float4*>(x + i + 4);
  short8 o;
  o[0] = (short)f2b(a.x); o[1] = (short)f2b(a.y); o[2] = (short)f2b(a.z); o[3] = (short)f2b(a.w);
  o[4] = (short)f2b(b.x); o[5] = (short)f2b(b.y); o[6] = (short)f2b(b.z); o[7] = (short)f2b(b.w);
  *reinterpret_cast<short8*>(xb + i) = o;
}

// ---- pack biases into one [1536] f32 buffer --------------------------------
__global__ void pack_bias_kern(const float* __restrict__ bq, const float* __restrict__ bk,
                               const float* __restrict__ bv, float* __restrict__ bc) {
  int i = blockIdx.x * 256 + threadIdx.x;
  float v = (i < 256) ? bq[i] : (i < 512) ? bk[i - 256] : bv[i - 512];
  bc[i] = v;
}

// ---- transpose f32 [R][C] -> bf16 [C][R], 64x64 tiles ----------------------
__global__ __launch_bounds__(256) void transpose_w_kern(const float* __restrict__ src,
                                                        unsigned short* __restrict__ dst,
                                                        int ldsrc, int lddst) {
  __shared__ __align__(16) unsigned short tile[64][72];
  int r0 = blockIdx.y * 64, c0 = blockIdx.x * 64;
  int t = threadIdx.x;
  #pragma unroll
  for (int it = 0; it < 4; ++it) {
    int idx = it * 1024 + t * 4;
    int row = idx >> 6, col = idx & 63;
    float4 v = *reinterpret_cast<const float4*>(src + (long)(r0 + row) * ldsrc + c0 + col);
    tile[row][col + 0] = f2b(v.x); tile[row][col + 1] = f2b(v.y);
    tile[row][col + 2] = f2b(v.z); tile[row][col + 3] = f2b(v.w);
  }
  __syncthreads();
  #pragma unroll
  for (int it = 0; it < 4; ++it) {
    int idx = it * 1024 + t * 4;
    int orow = idx >> 6, ocol = idx & 63;
    ushort4 o;
    o.x = tile[ocol + 0][orow]; o.y = tile[ocol + 1][orow];
    o.z = tile[ocol + 2][orow]; o.w = tile[ocol + 3][orow];
    *reinterpret_cast<ushort4*>(dst + (long)(c0 + orow) * lddst + r0 + ocol) = o;
  }
}

// ---- transpose bf16 [R][C] -> [C][R], batched (for V) ----------------------
__global__ __launch_bounds__(256) void transpose_v_kern(const unsigned short* __restrict__ src0,
                                                        unsigned short* __restrict__ dst0,
                                                        int ldsrc, int lddst,
                                                        long sbatch, long dbatch) {
  const unsigned short* src = src0 + (long)blockIdx.z * sbatch;
  unsigned short* dst = dst0 + (long)blockIdx.z * dbatch;
  __shared__ __align__(16) unsigned short tile[64][72];
  int r0 = blockIdx.y * 64, c0 = blockIdx.x * 64;
  int t = threadIdx.x;
  #pragma unroll
  for (int it = 0; it < 2; ++it) {
    int idx = it * 2048 + t * 8;
    int row = idx >> 6, col = idx & 63;
    short8 v = *reinterpret_cast<const short8*>(src + (long)(r0 + row) * ldsrc + c0 + col);
    *reinterpret_cast<short8*>(&tile[row][col]) = v;
  }
  __syncthreads();
  #pragma unroll
  for (int it = 0; it < 2; ++it) {
    int idx = it * 2048 + t * 8;
    int orow = idx >> 6, ocol = idx & 63;
    short8 o;
    #pragma unroll
    for (int i = 0; i < 8; ++i) o[i] = (short)tile[ocol + i][orow];
    *reinterpret_cast<short8*>(dst + (long)(c0 + orow) * lddst + r0 + ocol) = o;
  }
}

// ============================================================================
// Phase-scheduled GEMM: C[M][N] = A[M][K] * B[N][K]^T
// BM=128, BN=256, BK=64. 512 threads = 8 waves in 2(M)x4(N) grid, each wave
// owns a 64x64 output tile (acc[4][4]).
// 3-deep LDS pipeline (3 x (A 16KB + B 32KB) = 144KB), counted vmcnt(6)
// (= 6 global_load_lds per tile per wave), raw s_barrier (no __syncthreads
// drain in the main loop), XOR bank swizzle on LDS rows, setprio around MFMA.
// Safety argument: stage for tile t+2 targets buf[(t+2)%3], whose reads
// (tile t-1) were consumed by MFMAs before iter t-1's final barrier; the
// vmcnt wait for tile t+1 is issued before iter t's final barrier, so the
// reads at iter t+1 see complete data.
// ============================================================================
template <bool BF16OUT, bool BIAS, bool RS, bool EXPSUM>
__global__ __launch_bounds__(512, 2) void gemm8p(
    const unsigned short* __restrict__ A, const unsigned short* __restrict__ B,
    const float* __restrict__ bias, void* __restrict__ Cout,
    int ntilesN, int NT, int lda, int ldb, int ldc,
    long batchA, long batchB, long batchC,
    const float* __restrict__ rowscale, int rstride,
    float* __restrict__ lpart) {
  __shared__ __align__(128) unsigned short lds[3 * 24576];  // 3 x (8192 A + 16384 B) shorts
  const unsigned short* Ab = A + (long)blockIdx.z * batchA;
  const unsigned short* Bb = B + (long)blockIdx.z * batchB;

  // T1: bijective XCD swizzle (gridDim.x % 8 == 0 for all call sites)
  int nx = gridDim.x, bx = blockIdx.x;
  int sx = (bx & 7) * (nx >> 3) + (bx >> 3);
  int tm = sx / ntilesN, tn = sx % ntilesN;

  int t = threadIdx.x, w = t >> 6, l = t & 63;
  int wr = w >> 2, wc = w & 3;            // 2 x 4 wave grid
  int g = l >> 4, c = l & 15;

  f32x4 acc[4][4];
  #pragma unroll
  for (int m = 0; m < 4; ++m)
    #pragma unroll
    for (int n = 0; n < 4; ++n) acc[m][n] = (f32x4){0.f, 0.f, 0.f, 0.f};

  int srow = t >> 3;                      // 0..63 (row within 64-row round)
  int scb = (t & 7) * 16;                 // 16B chunk byte offset in 128B row

  const unsigned short* aptr = Ab + (long)(tm * 128) * lda;
  const unsigned short* bptr = Bb + (long)(tn * 256) * ldb;

  auto stageA = [&](int buf, int k0) {    // 2 gloads: 128 rows x 64 cols
    #pragma unroll
    for (int r = 0; r < 2; ++r) {
      int row = r * 64 + srow;
      int kb = scb ^ ((row & 7) << 4);    // inverse-swizzled global source
      gload16(aptr + (long)row * lda + k0 + (kb >> 1),
              lds + buf * 24576 + r * 4096 + w * 512);
    }
  };
  auto stageB = [&](int buf, int k0, int rlo, int rhi) {  // 256 rows x 64 cols
    #pragma unroll
    for (int r = 0; r < 4; ++r) {
      if (r < rlo || r >= rhi) continue;
      int row = r * 64 + srow;
      int kb = scb ^ ((row & 7) << 4);
      gload16(bptr + (long)row * ldb + k0 + (kb >> 1),
              lds + buf * 24576 + 8192 + r * 4096 + w * 512);
    }
  };

  // prologue: 2 tiles in flight, wait for tile 0 (leave tile 1's 6 loads)
  stageA(0, 0); stageB(0, 0, 0, 4);
  stageA(1, 64); stageB(1, 64, 0, 4);
  asm volatile("s_waitcnt vmcnt(6)" ::: "memory");
  __builtin_amdgcn_s_barrier();

  for (int kt = 0; kt < NT; ++kt) {
    int cur = kt % 3, nxt = (kt + 2) % 3;
    const char* abase = (const char*)(lds + cur * 24576);
    const char* bbase = abase + 16384;
    bool more = (kt + 2) < NT;
    int k2 = (kt + 2) * 64;
    #pragma unroll
    for (int subk = 0; subk < 2; ++subk) {
      bf16x8 af[4], bf[4];
      #pragma unroll
      for (int m = 0; m < 4; ++m) {
        int p = (wr * 64 + m * 16 + c) * 128 + (subk * 32 + g * 8) * 2;
        p ^= ((p >> 7) & 7) << 4;         // swizzled ds_read_b128
        af[m] = *reinterpret_cast<const bf16x8*>(abase + p);
      }
      #pragma unroll
      for (int n = 0; n < 4; ++n) {
        int p = (wc * 64 + n * 16 + c) * 128 + (subk * 32 + g * 8) * 2;
        p ^= ((p >> 7) & 7) << 4;
        bf[n] = *reinterpret_cast<const bf16x8*>(bbase + p);
      }
      if (more) {
        if (subk == 0) { stageA(nxt, k2); stageB(nxt, k2, 0, 1); }
        else           { stageB(nxt, k2, 1, 4); }
      }
      __builtin_amdgcn_s_barrier();
      __builtin_amdgcn_s_setprio(1);
      #pragma unroll
      for (int m = 0; m < 4; ++m)
        #pragma unroll
        for (int n = 0; n < 4; ++n)
          acc[m][n] = MFMA(af[m], bf[n], acc[m][n]);
      __builtin_amdgcn_s_setprio(0);
      if (subk == 1 && kt < NT - 1) {     // counted wait for tile kt+1
        if (kt == NT - 2) asm volatile("s_waitcnt vmcnt(0)" ::: "memory");
        else              asm volatile("s_waitcnt vmcnt(6)" ::: "memory");
      }
      __builtin_amdgcn_s_barrier();
    }
  }

  // ---- epilogue: C/D layout col = lane&15, row = (lane>>4)*4 + j ----
  int r0 = tm * 128 + wr * 64 + g * 4;
  int c0 = tn * 256 + wc * 64 + c;

  if constexpr (EXPSUM) {
    __shared__ float lred[4][128];
    #pragma unroll
    for (int m = 0; m < 4; ++m) {
      #pragma unroll
      for (int j = 0; j < 4; ++j) {
        long ob = (long)blockIdx.z * batchC + (long)(r0 + m * 16 + j) * ldc + c0;
        float rs = 0.f;
        #pragma unroll
        for (int n = 0; n < 4; ++n) {
          float pv = __expf(acc[m][n][j] * SCALE);
          ((unsigned short*)Cout)[ob + n * 16] = f2b(pv);
          rs += pv;
        }
        rs += __shfl_xor(rs, 1); rs += __shfl_xor(rs, 2);
        rs += __shfl_xor(rs, 4); rs += __shfl_xor(rs, 8);
        if (c == 0) lred[wc][wr * 64 + m * 16 + g * 4 + j] = rs;
      }
    }
    __syncthreads();
    if (t < 128) {
      float s = lred[0][t] + lred[1][t] + lred[2][t] + lred[3][t];
      lpart[((long)blockIdx.z * 2048 + tm * 128 + t) * 8 + tn] = s;
    }
  } else {
    #pragma unroll
    for (int m = 0; m < 4; ++m) {
      float lv[4];
      if (RS) {
        #pragma unroll
        for (int j = 0; j < 4; ++j)
          lv[j] = rowscale[(long)blockIdx.z * rstride + r0 + m * 16 + j];
      }
      #pragma unroll
      for (int n = 0; n < 4; ++n) {
        int col = c0 + n * 16;
        float bv = BIAS ? bias[col] : 0.f;
        long rowb = (long)blockIdx.z * batchC + (long)(r0 + m * 16) * ldc + col;
        #pragma unroll
        for (int j = 0; j < 4; ++j) {
          float v = acc[m][n][j] + bv;
          if (RS) v *= lv[j];
          if (BF16OUT) ((unsigned short*)Cout)[rowb + (long)j * ldc] = f2b(v);
          else         ((float*)Cout)[rowb + (long)j * ldc] = v;
        }
      }
    }
  }
}

// ---- 1/rowsum (8 partials per row) -----------------------------------------
__global__ __launch_bounds__(256) void linv_kern(const float* __restrict__ lpart,
                                                 float* __restrict__ linv) {
  int r = blockIdx.x * 256 + threadIdx.x;  // 8192 rows
  float s = 0.f;
  #pragma unroll
  for (int i = 0; i < 8; ++i) s += lpart[(long)r * 8 + i];
  linv[r] = 1.f / s;
}

extern "C" void kernel_launch(void* const* d_in, const int* in_sizes, int n_in,
                              void* d_out, int out_size, void* d_ws, size_t ws_size,
                              hipStream_t stream) {
  (void)in_sizes; (void)n_in; (void)out_size; (void)ws_size;
  const float* x  = (const float*)d_in[0];
  const float* Wq = (const float*)d_in[1];
  const float* bq = (const float*)d_in[2];
  const float* Wk = (const float*)d_in[3];
  const float* bk = (const float*)d_in[4];
  const float* Wv = (const float*)d_in[5];
  const float* bv = (const float*)d_in[6];
  float* out = (float*)d_out;
  char* ws = (char*)d_ws;

  // ws layout (bytes). lpart/linv overlay xb's region: xb is dead after the
  // QKV GEMM, and score/linv run strictly after it (stream-ordered).
  unsigned short* xb   = (unsigned short*)(ws + 0);          // 16,777,216
  float*          lpart= (float*)         (ws + 0);          //    262,144 (overlay)
  float*          linv = (float*)         (ws + 262144);     //     32,768 (overlay)
  unsigned short* wt   = (unsigned short*)(ws + 16777216);   //  3,145,728  [1536][1024]
  float*          bc   = (float*)         (ws + 19922944);   //      6,144
  unsigned short* qkv  = (unsigned short*)(ws + 19929088);   // 25,165,824  [8192][1536]
  unsigned short* vT   = (unsigned short*)(ws + 45094912);   // 16,777,216  [4][1024][2048]
  unsigned short* attn = (unsigned short*)(ws + 61872128);   // 33,554,432  [4][2048][2048]

  convert_x_kern<<<4096, 256, 0, stream>>>(x, xb);
  pack_bias_kern<<<6, 256, 0, stream>>>(bq, bk, bv, bc);
  transpose_w_kern<<<dim3(4, 16), 256, 0, stream>>>(Wq, wt,              256, 1024);
  transpose_w_kern<<<dim3(4, 16), 256, 0, stream>>>(Wk, wt + 256 * 1024, 256, 1024);
  transpose_w_kern<<<dim3(16, 16), 256, 0, stream>>>(Wv, wt + 512 * 1024, 1024, 1024);

  // qkv[8192][1536] = xb[8192][1024] @ wt[1536][1024]^T + bias
  gemm8p<true, true, false, false><<<dim3(384), 512, 0, stream>>>(
      xb, wt, bc, qkv, 6, 16, 1024, 1024, 1536, 0, 0, 0, nullptr, 0, nullptr);

  // vT[b][do][s] = v[b][s][do]
  transpose_v_kern<<<dim3(16, 32, 4), 256, 0, stream>>>(
      qkv + 512, vT, 1536, 2048, (long)2048 * 1536, (long)1024 * 2048);

  // attn[b][q][k] = exp(q.k/16) (unnormalized) + row partial sums
  gemm8p<true, false, false, true><<<dim3(128, 1, 4), 512, 0, stream>>>(
      qkv, qkv + 256, nullptr, attn, 8, 4, 1536, 1536, 2048,
      (long)2048 * 1536, (long)2048 * 1536, (long)2048 * 2048, nullptr, 0, lpart);
  linv_kern<<<32, 256, 0, stream>>>(lpart, linv);

  // out[b][s][do] = (attn[b][s][:] @ vT[b][do][:]^T) * linv[b][s]
  gemm8p<false, false, true, false><<<dim3(64, 1, 4), 512, 0, stream>>>(
      attn, vT, nullptr, out, 4, 32, 2048, 2048, 1024,
      (long)2048 * 2048, (long)1024 * 2048, (long)2048 * 1024, linv, 2048, nullptr);
}

// Round 4
// 127.030 us; speedup vs baseline: 1.0652x; 1.0652x over previous
//
#include <hip/hip_runtime.h>
#include <hip/hip_bf16.h>

typedef __attribute__((ext_vector_type(8))) short short8;
typedef __attribute__((ext_vector_type(8))) __bf16 bf16x8;
typedef __attribute__((ext_vector_type(4))) float f32x4;

#define MFMA(a, b, c) __builtin_amdgcn_mfma_f32_16x16x32_bf16((a), (b), (c), 0, 0, 0)
#define SCALE 0.0625f

static __device__ __forceinline__ void gload16(const void* g, void* l) {
  __builtin_amdgcn_global_load_lds(
      (const __attribute__((address_space(1))) void*)g,
      (__attribute__((address_space(3))) void*)l, 16, 0, 0);
}

static __device__ __forceinline__ unsigned short f2b(float f) {
  union { __hip_bfloat16 h; unsigned short u; } cv;
  cv.h = __float2bfloat16(f);
  return cv.u;
}

// ---- x (f32) -> bf16, 8 elems/thread ---------------------------------------
__global__ __launch_bounds__(256) void convert_x_kern(const float* __restrict__ x,
                                                      unsigned short* __restrict__ xb) {
  long i = ((long)blockIdx.x * 256 + threadIdx.x) * 8;
  float4 a = *reinterpret_cast<const float4*>(x + i);
  float4 b = *reinterpret_cast<const float4*>(x + i + 4);
  short8 o;
  o[0] = (short)f2b(a.x); o[1] = (short)f2b(a.y); o[2] = (short)f2b(a.z); o[3] = (short)f2b(a.w);
  o[4] = (short)f2b(b.x); o[5] = (short)f2b(b.y); o[6] = (short)f2b(b.z); o[7] = (short)f2b(b.w);
  *reinterpret_cast<short8*>(xb + i) = o;
}

// ---- pack biases into one [1536] f32 buffer --------------------------------
__global__ void pack_bias_kern(const float* __restrict__ bq, const float* __restrict__ bk,
                               const float* __restrict__ bv, float* __restrict__ bc) {
  int i = blockIdx.x * 256 + threadIdx.x;
  float v = (i < 256) ? bq[i] : (i < 512) ? bk[i - 256] : bv[i - 512];
  bc[i] = v;
}

// ---- transpose f32 [R][C] -> bf16 [C][R], 64x64 tiles ----------------------
__global__ __launch_bounds__(256) void transpose_w_kern(const float* __restrict__ src,
                                                        unsigned short* __restrict__ dst,
                                                        int ldsrc, int lddst) {
  __shared__ __align__(16) unsigned short tile[64][72];
  int r0 = blockIdx.y * 64, c0 = blockIdx.x * 64;
  int t = threadIdx.x;
  #pragma unroll
  for (int it = 0; it < 4; ++it) {
    int idx = it * 1024 + t * 4;
    int row = idx >> 6, col = idx & 63;
    float4 v = *reinterpret_cast<const float4*>(src + (long)(r0 + row) * ldsrc + c0 + col);
    tile[row][col + 0] = f2b(v.x); tile[row][col + 1] = f2b(v.y);
    tile[row][col + 2] = f2b(v.z); tile[row][col + 3] = f2b(v.w);
  }
  __syncthreads();
  #pragma unroll
  for (int it = 0; it < 4; ++it) {
    int idx = it * 1024 + t * 4;
    int orow = idx >> 6, ocol = idx & 63;
    ushort4 o;
    o.x = tile[ocol + 0][orow]; o.y = tile[ocol + 1][orow];
    o.z = tile[ocol + 2][orow]; o.w = tile[ocol + 3][orow];
    *reinterpret_cast<ushort4*>(dst + (long)(c0 + orow) * lddst + r0 + ocol) = o;
  }
}

// ---- transpose bf16 [R][C] -> [C][R], batched (for V) ----------------------
__global__ __launch_bounds__(256) void transpose_v_kern(const unsigned short* __restrict__ src0,
                                                        unsigned short* __restrict__ dst0,
                                                        int ldsrc, int lddst,
                                                        long sbatch, long dbatch) {
  const unsigned short* src = src0 + (long)blockIdx.z * sbatch;
  unsigned short* dst = dst0 + (long)blockIdx.z * dbatch;
  __shared__ __align__(16) unsigned short tile[64][72];
  int r0 = blockIdx.y * 64, c0 = blockIdx.x * 64;
  int t = threadIdx.x;
  #pragma unroll
  for (int it = 0; it < 2; ++it) {
    int idx = it * 2048 + t * 8;
    int row = idx >> 6, col = idx & 63;
    short8 v = *reinterpret_cast<const short8*>(src + (long)(r0 + row) * ldsrc + c0 + col);
    *reinterpret_cast<short8*>(&tile[row][col]) = v;
  }
  __syncthreads();
  #pragma unroll
  for (int it = 0; it < 2; ++it) {
    int idx = it * 2048 + t * 8;
    int orow = idx >> 6, ocol = idx & 63;
    short8 o;
    #pragma unroll
    for (int i = 0; i < 8; ++i) o[i] = (short)tile[ocol + i][orow];
    *reinterpret_cast<short8*>(dst + (long)(c0 + orow) * lddst + r0 + ocol) = o;
  }
}

// ============================================================================
// One-barrier-per-K-tile GEMM: C[M][N] = A[M][K] * B[N][K]^T
// BM=128, BN=256, BK=64. 512 threads = 8 waves in 2(M)x4(N), wave owns 64x64.
// Per K-tile: {issue all 16 ds_read_b128 (both k-halves) + 6 global_load_lds
// stages; compiler interleaves 32 MFMAs with fine-grained lgkmcnt; counted
// vmcnt(6); ONE s_barrier}. 3-deep LDS pipeline (144KB), XOR bank swizzle.
// Hazard audit: stage at iter t -> buf[(t+2)%3] == buf[(t-1)%3]; its reads
// were lgkm-retired before iter t-1's last MFMA and fenced by that iter's
// barrier, so the overwrite is ordered-safe with a single barrier per tile.
// ============================================================================
template <bool BF16OUT, bool BIAS, bool RS, bool EXPSUM>
__global__ __launch_bounds__(512, 2) void gemm1b(
    const unsigned short* __restrict__ A, const unsigned short* __restrict__ B,
    const float* __restrict__ bias, void* __restrict__ Cout,
    int ntilesN, int NT, int lda, int ldb, int ldc,
    long batchA, long batchB, long batchC,
    const float* __restrict__ rowscale, int rstride,
    float* __restrict__ lpart) {
  __shared__ __align__(128) unsigned short lds[3 * 24576];  // 3 x (8192 A + 16384 B) shorts
  const unsigned short* Ab = A + (long)blockIdx.z * batchA;
  const unsigned short* Bb = B + (long)blockIdx.z * batchB;

  // T1: bijective XCD swizzle (gridDim.x % 8 == 0 for all call sites)
  int nx = gridDim.x, bx = blockIdx.x;
  int sx = (bx & 7) * (nx >> 3) + (bx >> 3);
  int tm = sx / ntilesN, tn = sx % ntilesN;

  int t = threadIdx.x, w = t >> 6, l = t & 63;
  int wr = w >> 2, wc = w & 3;            // 2 x 4 wave grid
  int g = l >> 4, c = l & 15;

  f32x4 acc[4][4];
  #pragma unroll
  for (int m = 0; m < 4; ++m)
    #pragma unroll
    for (int n = 0; n < 4; ++n) acc[m][n] = (f32x4){0.f, 0.f, 0.f, 0.f};

  int srow = t >> 3;                      // 0..63 (row within 64-row round)
  int scb = (t & 7) * 16;                 // 16B chunk byte offset in 128B row

  const unsigned short* aptr = Ab + (long)(tm * 128) * lda;
  const unsigned short* bptr = Bb + (long)(tn * 256) * ldb;

  auto stageA = [&](int buf, int k0) {    // 2 gloads: 128 rows x 64 cols
    #pragma unroll
    for (int r = 0; r < 2; ++r) {
      int row = r * 64 + srow;
      int kb = scb ^ ((row & 7) << 4);    // inverse-swizzled global source
      gload16(aptr + (long)row * lda + k0 + (kb >> 1),
              lds + buf * 24576 + r * 4096 + w * 512);
    }
  };
  auto stageB = [&](int buf, int k0) {    // 4 gloads: 256 rows x 64 cols
    #pragma unroll
    for (int r = 0; r < 4; ++r) {
      int row = r * 64 + srow;
      int kb = scb ^ ((row & 7) << 4);
      gload16(bptr + (long)row * ldb + k0 + (kb >> 1),
              lds + buf * 24576 + 8192 + r * 4096 + w * 512);
    }
  };

  // prologue: 2 tiles in flight, wait for tile 0 (leave tile 1's 6 loads)
  stageA(0, 0); stageB(0, 0);
  stageA(1, 64); stageB(1, 64);
  asm volatile("s_waitcnt vmcnt(6)" ::: "memory");
  __builtin_amdgcn_s_barrier();

  for (int kt = 0; kt < NT; ++kt) {
    int cur = kt % 3, nxt = (kt + 2) % 3;
    const char* abase = (const char*)(lds + cur * 24576);
    const char* bbase = abase + 16384;

    // issue ALL fragment reads for both k-halves of this tile
    bf16x8 af[2][4], bf[2][4];
    #pragma unroll
    for (int sk = 0; sk < 2; ++sk) {
      #pragma unroll
      for (int m = 0; m < 4; ++m) {
        int p = (wr * 64 + m * 16 + c) * 128 + (sk * 32 + g * 8) * 2;
        p ^= ((p >> 7) & 7) << 4;         // swizzled ds_read_b128
        af[sk][m] = *reinterpret_cast<const bf16x8*>(abase + p);
      }
      #pragma unroll
      for (int n = 0; n < 4; ++n) {
        int p = (wc * 64 + n * 16 + c) * 128 + (sk * 32 + g * 8) * 2;
        p ^= ((p >> 7) & 7) << 4;
        bf[sk][n] = *reinterpret_cast<const bf16x8*>(bbase + p);
      }
    }

    // stage tile kt+2 while reads/MFMAs are in flight
    if (kt + 2 < NT) {
      int k2 = (kt + 2) * 64;
      stageA(nxt, k2); stageB(nxt, k2);
    }

    __builtin_amdgcn_s_setprio(1);
    #pragma unroll
    for (int sk = 0; sk < 2; ++sk)
      #pragma unroll
      for (int m = 0; m < 4; ++m)
        #pragma unroll
        for (int n = 0; n < 4; ++n)
          acc[m][n] = MFMA(af[sk][m], bf[sk][n], acc[m][n]);
    __builtin_amdgcn_s_setprio(0);

    if (kt < NT - 1) {                    // counted wait for tile kt+1, then ONE barrier
      if (kt == NT - 2) asm volatile("s_waitcnt vmcnt(0)" ::: "memory");
      else              asm volatile("s_waitcnt vmcnt(6)" ::: "memory");
      __builtin_amdgcn_s_barrier();
    }
  }

  // ---- epilogue: C/D layout col = lane&15, row = (lane>>4)*4 + j ----
  int r0 = tm * 128 + wr * 64 + g * 4;
  int c0 = tn * 256 + wc * 64 + c;

  if constexpr (EXPSUM) {
    __shared__ float lred[4][128];
    #pragma unroll
    for (int m = 0; m < 4; ++m) {
      #pragma unroll
      for (int j = 0; j < 4; ++j) {
        long ob = (long)blockIdx.z * batchC + (long)(r0 + m * 16 + j) * ldc + c0;
        float rs = 0.f;
        #pragma unroll
        for (int n = 0; n < 4; ++n) {
          float pv = __expf(acc[m][n][j] * SCALE);
          ((unsigned short*)Cout)[ob + n * 16] = f2b(pv);
          rs += pv;
        }
        rs += __shfl_xor(rs, 1); rs += __shfl_xor(rs, 2);
        rs += __shfl_xor(rs, 4); rs += __shfl_xor(rs, 8);
        if (c == 0) lred[wc][wr * 64 + m * 16 + g * 4 + j] = rs;
      }
    }
    __syncthreads();
    if (t < 128) {
      float s = lred[0][t] + lred[1][t] + lred[2][t] + lred[3][t];
      lpart[((long)blockIdx.z * 2048 + tm * 128 + t) * 8 + tn] = s;
    }
  } else {
    #pragma unroll
    for (int m = 0; m < 4; ++m) {
      float lv[4];
      if (RS) {
        #pragma unroll
        for (int j = 0; j < 4; ++j)
          lv[j] = rowscale[(long)blockIdx.z * rstride + r0 + m * 16 + j];
      }
      #pragma unroll
      for (int n = 0; n < 4; ++n) {
        int col = c0 + n * 16;
        float bv = BIAS ? bias[col] : 0.f;
        long rowb = (long)blockIdx.z * batchC + (long)(r0 + m * 16) * ldc + col;
        #pragma unroll
        for (int j = 0; j < 4; ++j) {
          float v = acc[m][n][j] + bv;
          if (RS) v *= lv[j];
          if (BF16OUT) ((unsigned short*)Cout)[rowb + (long)j * ldc] = f2b(v);
          else         ((float*)Cout)[rowb + (long)j * ldc] = v;
        }
      }
    }
  }
}

// ---- 1/rowsum (8 partials per row) -----------------------------------------
__global__ __launch_bounds__(256) void linv_kern(const float* __restrict__ lpart,
                                                 float* __restrict__ linv) {
  int r = blockIdx.x * 256 + threadIdx.x;  // 8192 rows
  float s = 0.f;
  #pragma unroll
  for (int i = 0; i < 8; ++i) s += lpart[(long)r * 8 + i];
  linv[r] = 1.f / s;
}

extern "C" void kernel_launch(void* const* d_in, const int* in_sizes, int n_in,
                              void* d_out, int out_size, void* d_ws, size_t ws_size,
                              hipStream_t stream) {
  (void)in_sizes; (void)n_in; (void)out_size; (void)ws_size;
  const float* x  = (const float*)d_in[0];
  const float* Wq = (const float*)d_in[1];
  const float* bq = (const float*)d_in[2];
  const float* Wk = (const float*)d_in[3];
  const float* bk = (const float*)d_in[4];
  const float* Wv = (const float*)d_in[5];
  const float* bv = (const float*)d_in[6];
  float* out = (float*)d_out;
  char* ws = (char*)d_ws;

  // ws layout (bytes). lpart/linv overlay xb's region: xb is dead after the
  // QKV GEMM, and score/linv run strictly after it (stream-ordered).
  unsigned short* xb   = (unsigned short*)(ws + 0);          // 16,777,216
  float*          lpart= (float*)         (ws + 0);          //    262,144 (overlay)
  float*          linv = (float*)         (ws + 262144);     //     32,768 (overlay)
  unsigned short* wt   = (unsigned short*)(ws + 16777216);   //  3,145,728  [1536][1024]
  float*          bc   = (float*)         (ws + 19922944);   //      6,144
  unsigned short* qkv  = (unsigned short*)(ws + 19929088);   // 25,165,824  [8192][1536]
  unsigned short* vT   = (unsigned short*)(ws + 45094912);   // 16,777,216  [4][1024][2048]
  unsigned short* attn = (unsigned short*)(ws + 61872128);   // 33,554,432  [4][2048][2048]

  convert_x_kern<<<4096, 256, 0, stream>>>(x, xb);
  pack_bias_kern<<<6, 256, 0, stream>>>(bq, bk, bv, bc);
  transpose_w_kern<<<dim3(4, 16), 256, 0, stream>>>(Wq, wt,              256, 1024);
  transpose_w_kern<<<dim3(4, 16), 256, 0, stream>>>(Wk, wt + 256 * 1024, 256, 1024);
  transpose_w_kern<<<dim3(16, 16), 256, 0, stream>>>(Wv, wt + 512 * 1024, 1024, 1024);

  // qkv[8192][1536] = xb[8192][1024] @ wt[1536][1024]^T + bias
  gemm1b<true, true, false, false><<<dim3(384), 512, 0, stream>>>(
      xb, wt, bc, qkv, 6, 16, 1024, 1024, 1536, 0, 0, 0, nullptr, 0, nullptr);

  // vT[b][do][s] = v[b][s][do]
  transpose_v_kern<<<dim3(16, 32, 4), 256, 0, stream>>>(
      qkv + 512, vT, 1536, 2048, (long)2048 * 1536, (long)1024 * 2048);

  // attn[b][q][k] = exp(q.k/16) (unnormalized) + row partial sums
  gemm1b<true, false, false, true><<<dim3(128, 1, 4), 512, 0, stream>>>(
      qkv, qkv + 256, nullptr, attn, 8, 4, 1536, 1536, 2048,
      (long)2048 * 1536, (long)2048 * 1536, (long)2048 * 2048, nullptr, 0, lpart);
  linv_kern<<<32, 256, 0, stream>>>(lpart, linv);

  // out[b][s][do] = (attn[b][s][:] @ vT[b][do][:]^T) * linv[b][s]
  gemm1b<false, false, true, false><<<dim3(64, 1, 4), 512, 0, stream>>>(
      attn, vT, nullptr, out, 4, 32, 2048, 2048, 1024,
      (long)2048 * 2048, (long)1024 * 2048, (long)2048 * 1024, linv, 2048, nullptr);
}